// Round 7
// baseline (585.474 us; speedup 1.0000x reference)
//
#include <hip/hip_runtime.h>
#include <hip/hip_bf16.h>

typedef unsigned short u16;
typedef __attribute__((ext_vector_type(8))) short short8;
typedef __attribute__((ext_vector_type(4))) float f32x4;

#define EPSV 1e-5f
#define ENC_NINF 0x007FFFFFu

__device__ __forceinline__ float bf2f(u16 u) {
    union { unsigned int i; float f; } v; v.i = ((unsigned int)u) << 16; return v.f;
}
__device__ __forceinline__ u16 f2bf(float f) {
    union { float f; unsigned int i; } v; v.f = f;
    unsigned int x = v.i;
    return (u16)((x + 0x7FFFu + ((x >> 16) & 1u)) >> 16);   // RNE
}
__device__ __forceinline__ unsigned int encbf(u16 u) {
    unsigned int f = ((unsigned int)u) << 16;
    return (f & 0x80000000u) ? ~f : (f | 0x80000000u);
}
__device__ __forceinline__ float dec(unsigned int u) {
    union { float f; unsigned int uu; } v;
    v.uu = (u & 0x80000000u) ? (u & 0x7FFFFFFFu) : ~u;
    return v.f;
}

// async 16B global -> LDS (per-lane source ok; LDS dest = uniform base + lane*16)
__device__ __forceinline__ void async16(const u16* g, u16* l) {
    __builtin_amdgcn_global_load_lds((const __attribute__((address_space(1))) void*)g,
                                     (__attribute__((address_space(3))) void*)l,
                                     16, 0, 0);
}

__global__ __launch_bounds__(256) void k_fillf(float* __restrict__ o, int n, float val)
{
    int i = blockIdx.x * 256 + threadIdx.x;
    if (i < n) o[i] = val;
}

// ---- adaptive repack: float tensors -> bf16 blob; choice -> clean int32 ----
struct Ptrs { const void* p[17]; int off[18]; int chN; };

__global__ __launch_bounds__(256) void k_repack(Ptrs P, const void* __restrict__ chSrc,
                                                int* __restrict__ chi, u16* __restrict__ rp,
                                                unsigned int* __restrict__ initp, int nU)
{
    const unsigned int* probe = (const unsigned int*)P.p[9];   // w3, |x| << 2
    int cnt = 0;
#pragma unroll
    for (int i = 0; i < 64; ++i) {
        unsigned int lo = probe[i] & 0xFFFFu;
        if (((lo >> 7) & 0xFFu) >= 0x80u) ++cnt;
    }
    const bool is_f32 = (cnt > 8);

    const unsigned int* cp = (const unsigned int*)chSrc;
    int z = 0; unsigned int mx = 0;
    for (int i = 0; i < 1024; ++i) {
        unsigned int w = cp[i];
        z += (w == 0u);
        mx = (w > mx) ? w : mx;
    }
    const int chMode = (mx >= 64u) ? 2 : ((z > 300) ? 1 : 0);  // 2=f32, 1=i64, 0=i32

    const int stride = gridDim.x * 256;
    const int gid0 = blockIdx.x * 256 + threadIdx.x;

    const int totalF = P.off[17];
    for (int g = gid0; g < totalF; g += stride) {
        int t = 0;
        while (g >= P.off[t + 1]) ++t;
        int off = g - P.off[t];
        u16 v;
        if (is_f32) v = f2bf(((const float*)P.p[t])[off]);
        else        v = ((const u16*)P.p[t])[off];
        rp[g] = v;
    }
    for (int i = gid0; i < P.chN; i += stride) {
        int v;
        if (chMode == 1)      v = (int)((const long long*)chSrc)[i];
        else if (chMode == 2) v = (int)((const float*)chSrc)[i];
        else                  v = ((const int*)chSrc)[i];
        chi[i] = v & 63;
    }
    for (int i = gid0; i < nU; i += stride) initp[i] = ENC_NINF;
}

// ---- counting sort per batch: points ordered by cluster ----
__global__ __launch_bounds__(256) void k_sort(const int* __restrict__ chi,
                                              int* __restrict__ schoice,
                                              int* __restrict__ perm)
{
    __shared__ int hist[64];
    __shared__ int base[64];
    const int b = blockIdx.x, tid = threadIdx.x;
    if (tid < 64) hist[tid] = 0;
    __syncthreads();
    const int o = b << 13;
    for (int i = tid; i < 8192; i += 256) atomicAdd(&hist[chi[o + i]], 1);
    __syncthreads();
    if (tid == 0) {
        int s = 0;
        for (int k = 0; k < 64; ++k) { base[k] = s; s += hist[k]; }
    }
    __syncthreads();
    for (int i = tid; i < 8192; i += 256) {
        int k = chi[o + i];
        int pos = atomicAdd(&base[k], 1);
        schoice[o + pos] = k;
        perm[o + pos] = o + i;
    }
}

// ---- G1 (NT=2): feat = (relu(bn1(xyz.w1^T+b1))) . w2^T + b2, seg-max fused ----
__global__ __launch_bounds__(256, 2) void g1_feat(
    const u16* __restrict__ xyz, const u16* __restrict__ w1, const u16* __restrict__ b1,
    const u16* __restrict__ g1v, const u16* __restrict__ bb1,
    const u16* __restrict__ m1, const u16* __restrict__ v1,
    const u16* __restrict__ w2, const u16* __restrict__ b2,
    const int* __restrict__ schoice, const int* __restrict__ perm,
    u16* __restrict__ feat, unsigned int* __restrict__ fg_u)
{
    __shared__ __align__(16) u16 Bs[256 * 128];      // 64 KB: both w2 halves
    __shared__ unsigned int lred[8 * 256];           // 8 KB (nk <= 8 fast path)
    __shared__ float4 pw[128];
    __shared__ float xs[128], ys[128], zs[128];
    __shared__ int chs[128];
    const int tid = threadIdx.x, lane = tid & 63, wave = tid >> 6;
    const int wm = (wave & 1) << 6, wn = (wave >> 1) << 6;
    const int m0 = blockIdx.x << 7;
    if (tid < 128) {
        float s = bf2f(g1v[tid]) * rsqrtf(bf2f(v1[tid]) + EPSV);
        float4 w;
        w.x = bf2f(w1[tid * 3 + 0]) * s;
        w.y = bf2f(w1[tid * 3 + 1]) * s;
        w.z = bf2f(w1[tid * 3 + 2]) * s;
        w.w = (bf2f(b1[tid]) - bf2f(m1[tid])) * s + bf2f(bb1[tid]);
        pw[tid] = w;
        const u16* p = xyz + (size_t)perm[m0 + tid] * 3;
        xs[tid] = bf2f(p[0]); ys[tid] = bf2f(p[1]); zs[tid] = bf2f(p[2]);
        chs[tid] = schoice[m0 + tid];
    }
    const int q = lane >> 4, mr = lane & 15;
    f32x4 acc[2][4][4] = {};
#pragma unroll
    for (int i = 0; i < 16; ++i) {
        int id = (i << 8) + tid, row = id >> 4, cc = id & 15;
        async16(w2 + (size_t)row * 128 + ((cc ^ (row & 15)) << 3), &Bs[id << 3]);
    }
    __syncthreads();
    const int kmin = chs[0], nk = chs[127] - kmin + 1;
    const bool useL = (nk <= 8);
    if (useL) for (int i = tid; i < (nk << 8); i += 256) lred[i] = ENC_NINF;
#pragma unroll
    for (int kk = 0; kk < 4; ++kk) {
        const int lc = kk * 4 + q;
        float4 wv[8];
#pragma unroll
        for (int j = 0; j < 8; ++j) wv[j] = pw[kk * 32 + q * 8 + j];
        short8 af[4];
#pragma unroll
        for (int mi = 0; mi < 4; ++mi) {
            int row = wm + mi * 16 + mr;
            float x = xs[row], y = ys[row], z = zs[row];
#pragma unroll
            for (int j = 0; j < 8; ++j) {
                float val = fmaf(x, wv[j].x, fmaf(y, wv[j].y, fmaf(z, wv[j].z, wv[j].w)));
                af[mi][j] = (short)f2bf(fmaxf(val, 0.0f));
            }
        }
#pragma unroll
        for (int h = 0; h < 2; ++h) {
            short8 bfr[4];
#pragma unroll
            for (int ni = 0; ni < 4; ++ni) {
                int r = (h << 7) + wn + ni * 16 + mr;
                bfr[ni] = *(const short8*)&Bs[r * 128 + ((lc ^ (r & 15)) << 3)];
            }
#pragma unroll
            for (int mi = 0; mi < 4; ++mi)
#pragma unroll
                for (int ni = 0; ni < 4; ++ni)
                    acc[h][mi][ni] = __builtin_amdgcn_mfma_f32_16x16x32_bf16(af[mi], bfr[ni], acc[h][mi][ni], 0, 0, 0);
        }
    }
    __syncthreads();
    const int colb = lane & 15;
    const int bl = m0 >> 13;
    unsigned int* db = fg_u + (size_t)(bl << 6) * 256;
#pragma unroll
    for (int h = 0; h < 2; ++h)
#pragma unroll
        for (int ni = 0; ni < 4; ++ni) {
            int n = (h << 7) + wn + (ni << 4) + colb;
            float bv = bf2f(b2[n]);
#pragma unroll
            for (int mi = 0; mi < 4; ++mi) {
                int curk = -1; unsigned int run = 0;
#pragma unroll
                for (int r = 0; r < 4; ++r) {
                    int rr = wm + (mi << 4) + (q << 2) + r;
                    u16 vb = f2bf(acc[h][mi][ni][r] + bv);
                    feat[(size_t)(m0 + rr) * 256 + n] = vb;
                    unsigned int e = encbf(vb);
                    int k = chs[rr];
                    if (k != curk) {
                        if (curk >= 0) {
                            if (useL) atomicMax(&lred[((curk - kmin) << 8) + n], run);
                            else      atomicMax(&db[curk * 256 + n], run);
                        }
                        curk = k; run = e;
                    } else run = run > e ? run : e;
                }
                if (useL) atomicMax(&lred[((curk - kmin) << 8) + n], run);
                else      atomicMax(&db[curk * 256 + n], run);
            }
        }
    if (useL) {
        __syncthreads();
        for (int i = tid; i < (nk << 8); i += 256) {
            unsigned int v = lred[i];
            if (v != ENC_NINF) atomicMax(&db[(kmin + (i >> 8)) * 256 + (i & 255)], v);
        }
    }
}

// ---- K_TH: th[b,c,n] = s_n * (fg[b,c,:] . w3[n, 0:256]) + t_n  (f32) ----
// The fg_pts half of f = [fg_pts|feat] has only 64 distinct rows per batch,
// so its contribution to h2 is a tiny per-cluster GEMM, hoisted out of g3.
// t_n = (b3-m2)*s + bb2 folded in; g3 then adds s*(feat.w3r^T) and relus.
// Rows of empty clusters are -inf -> garbage th rows, never gathered by g3.
__global__ __launch_bounds__(256, 2) void k_th(
    const u16* __restrict__ fg, const u16* __restrict__ w3, const u16* __restrict__ b3,
    const u16* __restrict__ g2, const u16* __restrict__ bb2,
    const u16* __restrict__ m2, const u16* __restrict__ v2,
    float* __restrict__ th)
{
    __shared__ __align__(16) u16 As[64 * 64];        // 8 KB
    __shared__ __align__(16) u16 Bs[256 * 64];       // 32 KB
    const int tid = threadIdx.x, lane = tid & 63, wave = tid >> 6;
    const int b = blockIdx.x, n0 = blockIdx.y << 8;
    const u16* fgb = fg + ((size_t)b << 14);         // b*64*256
    f32x4 acc[4][4] = {};
    for (int k0 = 0; k0 < 256; k0 += 64) {
        __syncthreads();
#pragma unroll
        for (int i = 0; i < 8; ++i) {                // w3l: 256 rows x 64 k
            int id = (i << 8) + tid, row = id >> 3, cc = id & 7;
            async16(w3 + (size_t)(n0 + row) * 512 + k0 + ((cc ^ (row & 7)) << 3),
                    &Bs[id << 3]);
        }
#pragma unroll
        for (int i = 0; i < 2; ++i) {                // fg: 64 rows x 64 k
            int id = (i << 8) + tid, row = id >> 3, cc = id & 7;
            async16(fgb + (size_t)row * 256 + k0 + ((cc ^ (row & 7)) << 3),
                    &As[id << 3]);
        }
        __syncthreads();
        const int q = lane >> 4, mr = lane & 15;
#pragma unroll
        for (int kk = 0; kk < 2; ++kk) {
            const int lc = (kk << 2) + q;
            short8 af[4], bfr[4];
#pragma unroll
            for (int mi = 0; mi < 4; ++mi) {
                int r = (mi << 4) + mr;
                af[mi] = *(const short8*)&As[r * 64 + ((lc ^ (r & 7)) << 3)];
            }
#pragma unroll
            for (int ni = 0; ni < 4; ++ni) {
                int r = (wave << 6) + (ni << 4) + mr;
                bfr[ni] = *(const short8*)&Bs[r * 64 + ((lc ^ (r & 7)) << 3)];
            }
#pragma unroll
            for (int mi = 0; mi < 4; ++mi)
#pragma unroll
                for (int ni = 0; ni < 4; ++ni)
                    acc[mi][ni] = __builtin_amdgcn_mfma_f32_16x16x32_bf16(af[mi], bfr[ni], acc[mi][ni], 0, 0, 0);
        }
    }
    const int q = lane >> 4, colb = lane & 15;
#pragma unroll
    for (int ni = 0; ni < 4; ++ni) {
        int n = n0 + (wave << 6) + (ni << 4) + colb;
        float s = bf2f(g2[n]) * rsqrtf(bf2f(v2[n]) + EPSV);
        float t = (bf2f(b3[n]) - bf2f(m2[n])) * s + bf2f(bb2[n]);
#pragma unroll
        for (int mi = 0; mi < 4; ++mi)
#pragma unroll
            for (int r = 0; r < 4; ++r) {
                int c = (mi << 4) + (q << 2) + r;
                th[((size_t)(b << 6) + c) * 512 + n] = fmaf(acc[mi][ni][r], s, t);
            }
    }
}

// ---- G3: h2 = relu(s * (feat . w3[:,256:]^T) + th[choice]), K=256 ----
// K halved vs baseline (fg half hoisted into k_th): MFMA + staging halve.
__global__ __launch_bounds__(256, 2) void g3_h2(
    const int* __restrict__ schoice, const u16* __restrict__ feat,
    const float* __restrict__ th, const u16* __restrict__ w3,
    const u16* __restrict__ g2, const u16* __restrict__ v2,
    u16* __restrict__ h2)
{
    __shared__ __align__(16) u16 As[128 * 64];
    __shared__ __align__(16) u16 Bs[2 * 128 * 64];
    __shared__ int chs[128];
    const int tid = threadIdx.x, lane = tid & 63, wave = tid >> 6;
    const int wm = (wave & 1) << 6, wn = (wave >> 1) << 6;
    const int m0 = blockIdx.x << 7, n0 = blockIdx.y << 8;   // 256-wide N group
    const int c = tid & 7, rb = tid >> 3;
    if (tid < 128) chs[tid] = schoice[m0 + tid];
    const u16* ftrow[4];
#pragma unroll
    for (int i = 0; i < 4; ++i)
        ftrow[i] = feat + ((size_t)(m0 + rb + (i << 5)) << 8);
    f32x4 acc[2][4][4] = {};
    for (int k0 = 0; k0 < 256; k0 += 64) {
        __syncthreads();
#pragma unroll
        for (int nt = 0; nt < 2; ++nt)
#pragma unroll
            for (int i = 0; i < 4; ++i) {
                int id = (i << 8) + tid, row = id >> 3, cc = id & 7;
                async16(w3 + (size_t)(n0 + nt * 128 + row) * 512 + 256 + k0
                            + ((cc ^ (row & 7)) << 3),
                        &Bs[nt * 8192 + (id << 3)]);
            }
#pragma unroll
        for (int i = 0; i < 4; ++i) {
            int r = rb + (i << 5);
            async16(ftrow[i] + k0 + ((c ^ (r & 7)) << 3), &As[(((i << 8) + tid) << 3)]);
        }
        __syncthreads();
        const int q = lane >> 4, mr = lane & 15;
#pragma unroll
        for (int kk = 0; kk < 2; ++kk) {
            short8 af[4];
            const int lc = kk * 4 + q;
#pragma unroll
            for (int mi = 0; mi < 4; ++mi) {
                int r = wm + mi * 16 + mr;
                af[mi] = *(const short8*)&As[r * 64 + ((lc ^ (r & 7)) << 3)];
            }
#pragma unroll
            for (int nt = 0; nt < 2; ++nt) {
                short8 bfr[4];
#pragma unroll
                for (int ni = 0; ni < 4; ++ni) {
                    int r = wn + ni * 16 + mr;
                    bfr[ni] = *(const short8*)&Bs[nt * 8192 + r * 64 + ((lc ^ (r & 7)) << 3)];
                }
#pragma unroll
                for (int mi = 0; mi < 4; ++mi)
#pragma unroll
                    for (int ni = 0; ni < 4; ++ni)
                        acc[nt][mi][ni] = __builtin_amdgcn_mfma_f32_16x16x32_bf16(af[mi], bfr[ni], acc[nt][mi][ni], 0, 0, 0);
            }
        }
    }
    const int q = lane >> 4, colb = lane & 15;
    const float* thb = th + ((size_t)((m0 >> 13) << 6) * 512);
#pragma unroll
    for (int nt = 0; nt < 2; ++nt)
#pragma unroll
        for (int ni = 0; ni < 4; ++ni) {
            int n = n0 + nt * 128 + wn + (ni << 4) + colb;
            float s = bf2f(g2[n]) * rsqrtf(bf2f(v2[n]) + EPSV);
#pragma unroll
            for (int mi = 0; mi < 4; ++mi)
#pragma unroll
                for (int r = 0; r < 4; ++r) {
                    int rr = wm + (mi << 4) + (q << 2) + r;
                    float thv = thb[(size_t)chs[rr] * 512 + n];
                    h2[(size_t)(m0 + rr) * 512 + n] =
                        f2bf(fmaxf(fmaf(acc[nt][mi][ni][r], s, thv), 0.0f));
                }
        }
}

// ---- G4: out = h2 . w4^T + b4, M=128, N=384, 512 thr, w4 in 192-row chunks ----
// R6 measured a ~128 KB usable-LDS/CU limit (64.5 KB -> 1 block -> 22% occ).
// 40.5 KB (As 16K + Bs 24K) -> 3 blocks/CU -> 24 waves (75%). Same staged bytes.
// Regs: 76 arch + 96 AGPR = 172 <= 256 (validated R6, unchanged inner loop).
__global__ __launch_bounds__(512, 2) void g4_out(
    const u16* __restrict__ A, const u16* __restrict__ w4,
    const u16* __restrict__ bias, const int* __restrict__ schoice,
    unsigned int* __restrict__ out_u)
{
    __shared__ __align__(16) u16 As[128 * 64];       // 16 KB (persists across chunks)
    __shared__ __align__(16) u16 Bs[192 * 64];       // 24 KB (w4 row-chunk)
    __shared__ int chs[128];
    const int tid = threadIdx.x, lane = tid & 63, wave = tid >> 6;
    const int wm = (wave & 1) << 6, wn48 = (wave >> 1) * 48;
    const int m0 = blockIdx.x << 7;
    if (tid < 128) chs[tid] = schoice[m0 + tid];
    f32x4 acc[4][6] = {};
    for (int k0 = 0; k0 < 512; k0 += 64) {
#pragma unroll
        for (int cch = 0; cch < 2; ++cch) {          // w4 rows cch*192..+192
            __syncthreads();                         // prior reads of As/Bs done
            if (cch == 0)
#pragma unroll
                for (int i = 0; i < 2; ++i) {        // h2: 128 rows x 8 chunks
                    int id = (i << 9) + tid, row = id >> 3, cc = id & 7;
                    async16(A + (size_t)(m0 + row) * 512 + k0 + ((cc ^ (row & 7)) << 3),
                            &As[id << 3]);
                }
#pragma unroll
            for (int i = 0; i < 3; ++i) {            // w4 chunk: 192 rows x 8 chunks
                int id = (i << 9) + tid, row = id >> 3, cc = id & 7;
                async16(w4 + (size_t)(cch * 192 + row) * 512 + k0 + ((cc ^ (row & 7)) << 3),
                        &Bs[id << 3]);
            }
            __syncthreads();
            const int q = lane >> 4, mr = lane & 15;
#pragma unroll
            for (int kk = 0; kk < 2; ++kk) {
                const int lc = (kk << 2) + q;
                short8 af[4];
#pragma unroll
                for (int mi = 0; mi < 4; ++mi) {
                    int r = wm + (mi << 4) + mr;
                    af[mi] = *(const short8*)&As[r * 64 + ((lc ^ (r & 7)) << 3)];
                }
#pragma unroll
                for (int ni = 0; ni < 3; ++ni) {
                    int r = wn48 + (ni << 4) + mr;   // 0..191 within chunk
                    short8 bfr = *(const short8*)&Bs[r * 64 + ((lc ^ (r & 7)) << 3)];
#pragma unroll
                    for (int mi = 0; mi < 4; ++mi)
                        acc[mi][cch * 3 + ni] = __builtin_amdgcn_mfma_f32_16x16x32_bf16(af[mi], bfr, acc[mi][cch * 3 + ni], 0, 0, 0);
                }
            }
        }
    }
    // ---- fused seg-max epilogue ----
    __syncthreads();                                 // staging reads done; reuse smem
    unsigned int* lred = (unsigned int*)As;          // As+Bs = 40 KB = 10240 u32
    const int kmin = chs[0], nk = chs[127] - kmin + 1;
    const bool useL = (nk <= 26);                    // nk*384 <= 10240
    const int bl = m0 >> 13;
    unsigned int* db = out_u + (size_t)(bl << 6) * 384;
    if (useL) for (int i = tid; i < nk * 384; i += 512) lred[i] = ENC_NINF;
    __syncthreads();
    const int q = lane >> 4, colb = lane & 15;
#pragma unroll
    for (int j = 0; j < 6; ++j) {
        int nc = (j < 3 ? 0 : 192) + wn48 + ((j < 3 ? j : j - 3) << 4) + colb;
        float bv = bf2f(bias[nc]);
#pragma unroll
        for (int mi = 0; mi < 4; ++mi) {
            int curk = -1; unsigned int run = 0;
#pragma unroll
            for (int r = 0; r < 4; ++r) {
                int rr = wm + (mi << 4) + (q << 2) + r;
                unsigned int e = encbf(f2bf(acc[mi][j][r] + bv));
                int k = chs[rr];
                if (k != curk) {
                    if (curk >= 0) {
                        if (useL) atomicMax(&lred[(curk - kmin) * 384 + nc], run);
                        else      atomicMax(&db[curk * 384 + nc], run);
                    }
                    curk = k; run = e;
                } else run = run > e ? run : e;
            }
            if (useL) atomicMax(&lred[(curk - kmin) * 384 + nc], run);
            else      atomicMax(&db[curk * 384 + nc], run);
        }
    }
    if (useL) {
        __syncthreads();
        for (int i = tid; i < nk * 384; i += 512) {
            unsigned int v = lred[i];
            if (v != ENC_NINF) {
                int kq = i / 384;
                atomicMax(&db[(kmin + kq) * 384 + (i - kq * 384)], v);
            }
        }
    }
}

__global__ __launch_bounds__(256) void k_dec_bf(const unsigned int* __restrict__ u,
                                                u16* __restrict__ o, int n)
{
    int i = blockIdx.x * 256 + threadIdx.x;
    if (i < n) o[i] = f2bf(dec(u[i]));
}
__global__ __launch_bounds__(256) void k_dec_f32(const unsigned int* __restrict__ u,
                                                 float* __restrict__ o, int n)
{
    int i = blockIdx.x * 256 + threadIdx.x;
    if (i < n) o[i] = dec(u[i]);
}

extern "C" void kernel_launch(void* const* d_in, const int* in_sizes, int n_in,
                              void* d_out, int out_size, void* d_ws, size_t ws_size,
                              hipStream_t stream)
{
    float* out = (float*)d_out;
    if (n_in != 18) {
        k_fillf<<<dim3((out_size + 255) / 256), 256, 0, stream>>>(out, out_size, 1000.0f);
        return;
    }

    const int map[17] = {0, 2, 3, 4, 5, 6, 7, 8, 9, 10, 11, 12, 13, 14, 15, 16, 17};
    Ptrs P;
    P.off[0] = 0;
    for (int i = 0; i < 17; ++i) {
        P.p[i] = d_in[map[i]];
        P.off[i + 1] = P.off[i] + in_sizes[map[i]];
    }
    P.chN = in_sizes[1];

    char* ws = (char*)d_ws;
    int* chi = (int*)ws;
    const size_t chiB = ((size_t)P.chN * 4 + 255) & ~255ull;
    int* schoice = (int*)(ws + chiB);
    int* perm    = (int*)(ws + 2 * chiB);
    u16* rp = (u16*)(ws + 3 * chiB);
    const size_t rpB = ((size_t)P.off[17] * 2 + 255) & ~255ull;
    const size_t RPB = 3 * chiB + rpB;

    // fixed region: fg_u (32*64*256 u32) + out_u (32*64*384 u32) = 5,242,880 B
    unsigned int* fg_u_all  = (unsigned int*)(ws + RPB);
    unsigned int* out_u_all = fg_u_all + 32 * 64 * 256;
    const size_t UB = 5242880ull;
    const int nU = 32 * 64 * 640;

    k_repack<<<dim3(1024), 256, 0, stream>>>(P, d_in[1], chi, rp, fg_u_all, nU);
    k_sort<<<dim3(P.chN >> 13), 256, 0, stream>>>(chi, schoice, perm);

    const u16* xyz  = rp + P.off[0];
    const u16* w1   = rp + P.off[1];
    const u16* b1   = rp + P.off[2];
    const u16* bn1g = rp + P.off[3];
    const u16* bn1b = rp + P.off[4];
    const u16* bn1m = rp + P.off[5];
    const u16* bn1v = rp + P.off[6];
    const u16* w2   = rp + P.off[7];
    const u16* b2   = rp + P.off[8];
    const u16* w3   = rp + P.off[9];
    const u16* b3   = rp + P.off[10];
    const u16* bn2g = rp + P.off[11];
    const u16* bn2b = rp + P.off[12];
    const u16* bn2m = rp + P.off[13];
    const u16* bn2v = rp + P.off[14];
    const u16* w4   = rp + P.off[15];
    const u16* b4   = rp + P.off[16];

    // per-batch: feat 4,194,304 + h2 8,388,608 + fg 32,768 + th 131,072 = 12,746,752
    const size_t PB = 12746752ull;
    int sb = 32;
    while (sb > 1 && RPB + UB + (size_t)sb * PB > ws_size) sb >>= 1;
    if (RPB + UB + PB > ws_size) {
        k_fillf<<<dim3((out_size + 255) / 256), 256, 0, stream>>>(out, out_size, 3000.0f);
        return;
    }
    const int ns = 32 / sb;

    char* wsb = ws + RPB + UB;
    const size_t featB = (size_t)sb * 8192 * 256 * 2;
    const size_t h2B   = (size_t)sb * 8192 * 512 * 2;
    const size_t fgB   = (size_t)sb * 64 * 256 * 2;
    u16* feat = (u16*)(wsb);
    u16* h2s  = (u16*)(wsb + featB);
    u16* fg   = (u16*)(wsb + featB + h2B);
    float* th = (float*)(wsb + featB + h2B + fgB);

    const int mblk = sb << 6;        // 128-row M-tiles (g1, g3, g4)
    const int nfg = sb * 64 * 256;
    const int nou = sb * 64 * 384;
    for (int s = 0; s < ns; ++s) {
        const int b0 = s * sb;
        const int pt0 = b0 << 13;
        const int* sch_sl = schoice + pt0;
        const int* perm_sl = perm + pt0;
        unsigned int* fg_u  = fg_u_all + (size_t)b0 * 64 * 256;
        unsigned int* out_u = out_u_all + (size_t)b0 * 64 * 384;
        g1_feat<<<dim3(mblk), 256, 0, stream>>>(xyz, w1, b1, bn1g, bn1b, bn1m, bn1v,
                                                w2, b2, sch_sl, perm_sl, feat, fg_u);
        k_dec_bf<<<dim3((nfg + 255) / 256), 256, 0, stream>>>(fg_u, fg, nfg);
        k_th<<<dim3(sb, 2), 256, 0, stream>>>(fg, w3, b3, bn2g, bn2b, bn2m, bn2v, th);
        g3_h2<<<dim3(mblk, 2), 256, 0, stream>>>(sch_sl, feat, th, w3,
                                                 bn2g, bn2v, h2s);
        g4_out<<<dim3(mblk), 512, 0, stream>>>(h2s, w4, b4, sch_sl, out_u);
        k_dec_f32<<<dim3((nou + 255) / 256), 256, 0, stream>>>(out_u,
                                                               out + ((size_t)b0 << 6) * 384, nou);
    }
}

// Round 8
// 563.317 us; speedup vs baseline: 1.0393x; 1.0393x over previous
//
#include <hip/hip_runtime.h>
#include <hip/hip_bf16.h>

typedef unsigned short u16;
typedef __attribute__((ext_vector_type(8))) short short8;
typedef __attribute__((ext_vector_type(4))) float f32x4;

#define EPSV 1e-5f
#define ENC_NINF 0x007FFFFFu

__device__ __forceinline__ float bf2f(u16 u) {
    union { unsigned int i; float f; } v; v.i = ((unsigned int)u) << 16; return v.f;
}
__device__ __forceinline__ u16 f2bf(float f) {
    union { float f; unsigned int i; } v; v.f = f;
    unsigned int x = v.i;
    return (u16)((x + 0x7FFFu + ((x >> 16) & 1u)) >> 16);   // RNE
}
__device__ __forceinline__ unsigned int encbf(u16 u) {
    unsigned int f = ((unsigned int)u) << 16;
    return (f & 0x80000000u) ? ~f : (f | 0x80000000u);
}
__device__ __forceinline__ float dec(unsigned int u) {
    union { float f; unsigned int uu; } v;
    v.uu = (u & 0x80000000u) ? (u & 0x7FFFFFFFu) : ~u;
    return v.f;
}

// async 16B global -> LDS (per-lane source ok; LDS dest = uniform base + lane*16)
__device__ __forceinline__ void async16(const u16* g, u16* l) {
    __builtin_amdgcn_global_load_lds((const __attribute__((address_space(1))) void*)g,
                                     (__attribute__((address_space(3))) void*)l,
                                     16, 0, 0);
}

__global__ __launch_bounds__(256) void k_fillf(float* __restrict__ o, int n, float val)
{
    int i = blockIdx.x * 256 + threadIdx.x;
    if (i < n) o[i] = val;
}

// ---- adaptive repack: float tensors -> bf16 blob; choice -> clean int32 ----
struct Ptrs { const void* p[17]; int off[18]; int chN; };

__global__ __launch_bounds__(256) void k_repack(Ptrs P, const void* __restrict__ chSrc,
                                                int* __restrict__ chi, u16* __restrict__ rp,
                                                unsigned int* __restrict__ initp, int nU)
{
    const unsigned int* probe = (const unsigned int*)P.p[9];   // w3, |x| << 2
    int cnt = 0;
#pragma unroll
    for (int i = 0; i < 64; ++i) {
        unsigned int lo = probe[i] & 0xFFFFu;
        if (((lo >> 7) & 0xFFu) >= 0x80u) ++cnt;
    }
    const bool is_f32 = (cnt > 8);

    const unsigned int* cp = (const unsigned int*)chSrc;
    int z = 0; unsigned int mx = 0;
    for (int i = 0; i < 1024; ++i) {
        unsigned int w = cp[i];
        z += (w == 0u);
        mx = (w > mx) ? w : mx;
    }
    const int chMode = (mx >= 64u) ? 2 : ((z > 300) ? 1 : 0);  // 2=f32, 1=i64, 0=i32

    const int stride = gridDim.x * 256;
    const int gid0 = blockIdx.x * 256 + threadIdx.x;

    const int totalF = P.off[17];
    for (int g = gid0; g < totalF; g += stride) {
        int t = 0;
        while (g >= P.off[t + 1]) ++t;
        int off = g - P.off[t];
        u16 v;
        if (is_f32) v = f2bf(((const float*)P.p[t])[off]);
        else        v = ((const u16*)P.p[t])[off];
        rp[g] = v;
    }
    for (int i = gid0; i < P.chN; i += stride) {
        int v;
        if (chMode == 1)      v = (int)((const long long*)chSrc)[i];
        else if (chMode == 2) v = (int)((const float*)chSrc)[i];
        else                  v = ((const int*)chSrc)[i];
        chi[i] = v & 63;
    }
    for (int i = gid0; i < nU; i += stride) initp[i] = ENC_NINF;
}

// ---- counting sort per batch: points ordered by cluster ----
__global__ __launch_bounds__(256) void k_sort(const int* __restrict__ chi,
                                              int* __restrict__ schoice,
                                              int* __restrict__ perm)
{
    __shared__ int hist[64];
    __shared__ int base[64];
    const int b = blockIdx.x, tid = threadIdx.x;
    if (tid < 64) hist[tid] = 0;
    __syncthreads();
    const int o = b << 13;
    for (int i = tid; i < 8192; i += 256) atomicAdd(&hist[chi[o + i]], 1);
    __syncthreads();
    if (tid == 0) {
        int s = 0;
        for (int k = 0; k < 64; ++k) { base[k] = s; s += hist[k]; }
    }
    __syncthreads();
    for (int i = tid; i < 8192; i += 256) {
        int k = chi[o + i];
        int pos = atomicAdd(&base[k], 1);
        schoice[o + pos] = k;
        perm[o + pos] = o + i;
    }
}

// ---- G1 (NT=2): feat = (relu(bn1(xyz.w1^T+b1))) . w2^T + b2, seg-max fused ----
__global__ __launch_bounds__(256, 2) void g1_feat(
    const u16* __restrict__ xyz, const u16* __restrict__ w1, const u16* __restrict__ b1,
    const u16* __restrict__ g1v, const u16* __restrict__ bb1,
    const u16* __restrict__ m1, const u16* __restrict__ v1,
    const u16* __restrict__ w2, const u16* __restrict__ b2,
    const int* __restrict__ schoice, const int* __restrict__ perm,
    u16* __restrict__ feat, unsigned int* __restrict__ fg_u)
{
    __shared__ __align__(16) u16 Bs[256 * 128];      // 64 KB: both w2 halves
    __shared__ unsigned int lred[8 * 256];           // 8 KB (nk <= 8 fast path)
    __shared__ float4 pw[128];
    __shared__ float xs[128], ys[128], zs[128];
    __shared__ int chs[128];
    const int tid = threadIdx.x, lane = tid & 63, wave = tid >> 6;
    const int wm = (wave & 1) << 6, wn = (wave >> 1) << 6;
    const int m0 = blockIdx.x << 7;
    if (tid < 128) {
        float s = bf2f(g1v[tid]) * rsqrtf(bf2f(v1[tid]) + EPSV);
        float4 w;
        w.x = bf2f(w1[tid * 3 + 0]) * s;
        w.y = bf2f(w1[tid * 3 + 1]) * s;
        w.z = bf2f(w1[tid * 3 + 2]) * s;
        w.w = (bf2f(b1[tid]) - bf2f(m1[tid])) * s + bf2f(bb1[tid]);
        pw[tid] = w;
        const u16* p = xyz + (size_t)perm[m0 + tid] * 3;
        xs[tid] = bf2f(p[0]); ys[tid] = bf2f(p[1]); zs[tid] = bf2f(p[2]);
        chs[tid] = schoice[m0 + tid];
    }
    const int q = lane >> 4, mr = lane & 15;
    f32x4 acc[2][4][4] = {};
#pragma unroll
    for (int i = 0; i < 16; ++i) {
        int id = (i << 8) + tid, row = id >> 4, cc = id & 15;
        async16(w2 + (size_t)row * 128 + ((cc ^ (row & 15)) << 3), &Bs[id << 3]);
    }
    __syncthreads();
    const int kmin = chs[0], nk = chs[127] - kmin + 1;
    const bool useL = (nk <= 8);
    if (useL) for (int i = tid; i < (nk << 8); i += 256) lred[i] = ENC_NINF;
#pragma unroll
    for (int kk = 0; kk < 4; ++kk) {
        const int lc = kk * 4 + q;
        float4 wv[8];
#pragma unroll
        for (int j = 0; j < 8; ++j) wv[j] = pw[kk * 32 + q * 8 + j];
        short8 af[4];
#pragma unroll
        for (int mi = 0; mi < 4; ++mi) {
            int row = wm + mi * 16 + mr;
            float x = xs[row], y = ys[row], z = zs[row];
#pragma unroll
            for (int j = 0; j < 8; ++j) {
                float val = fmaf(x, wv[j].x, fmaf(y, wv[j].y, fmaf(z, wv[j].z, wv[j].w)));
                af[mi][j] = (short)f2bf(fmaxf(val, 0.0f));
            }
        }
#pragma unroll
        for (int h = 0; h < 2; ++h) {
            short8 bfr[4];
#pragma unroll
            for (int ni = 0; ni < 4; ++ni) {
                int r = (h << 7) + wn + ni * 16 + mr;
                bfr[ni] = *(const short8*)&Bs[r * 128 + ((lc ^ (r & 15)) << 3)];
            }
#pragma unroll
            for (int mi = 0; mi < 4; ++mi)
#pragma unroll
                for (int ni = 0; ni < 4; ++ni)
                    acc[h][mi][ni] = __builtin_amdgcn_mfma_f32_16x16x32_bf16(af[mi], bfr[ni], acc[h][mi][ni], 0, 0, 0);
        }
    }
    __syncthreads();
    const int colb = lane & 15;
    const int bl = m0 >> 13;
    unsigned int* db = fg_u + (size_t)(bl << 6) * 256;
#pragma unroll
    for (int h = 0; h < 2; ++h)
#pragma unroll
        for (int ni = 0; ni < 4; ++ni) {
            int n = (h << 7) + wn + (ni << 4) + colb;
            float bv = bf2f(b2[n]);
#pragma unroll
            for (int mi = 0; mi < 4; ++mi) {
                int curk = -1; unsigned int run = 0;
#pragma unroll
                for (int r = 0; r < 4; ++r) {
                    int rr = wm + (mi << 4) + (q << 2) + r;
                    u16 vb = f2bf(acc[h][mi][ni][r] + bv);
                    feat[(size_t)(m0 + rr) * 256 + n] = vb;
                    unsigned int e = encbf(vb);
                    int k = chs[rr];
                    if (k != curk) {
                        if (curk >= 0) {
                            if (useL) atomicMax(&lred[((curk - kmin) << 8) + n], run);
                            else      atomicMax(&db[curk * 256 + n], run);
                        }
                        curk = k; run = e;
                    } else run = run > e ? run : e;
                }
                if (useL) atomicMax(&lred[((curk - kmin) << 8) + n], run);
                else      atomicMax(&db[curk * 256 + n], run);
            }
        }
    if (useL) {
        __syncthreads();
        for (int i = tid; i < (nk << 8); i += 256) {
            unsigned int v = lred[i];
            if (v != ENC_NINF) atomicMax(&db[(kmin + (i >> 8)) * 256 + (i & 255)], v);
        }
    }
}

// ---- K_TH: th[b,c,n] = s_n * (fg[b,c,:] . w3[n, 0:256]) + t_n  (f32) ----
// fg_pts half of f = [fg_pts|feat] has only 64 distinct rows per batch ->
// its h2 contribution is a tiny per-cluster GEMM hoisted out of the main pass.
__global__ __launch_bounds__(256, 2) void k_th(
    const u16* __restrict__ fg, const u16* __restrict__ w3, const u16* __restrict__ b3,
    const u16* __restrict__ g2, const u16* __restrict__ bb2,
    const u16* __restrict__ m2, const u16* __restrict__ v2,
    float* __restrict__ th)
{
    __shared__ __align__(16) u16 As[64 * 64];        // 8 KB
    __shared__ __align__(16) u16 Bs[256 * 64];       // 32 KB
    const int tid = threadIdx.x, lane = tid & 63, wave = tid >> 6;
    const int b = blockIdx.x, n0 = blockIdx.y << 8;
    const u16* fgb = fg + ((size_t)b << 14);         // b*64*256
    f32x4 acc[4][4] = {};
    for (int k0 = 0; k0 < 256; k0 += 64) {
        __syncthreads();
#pragma unroll
        for (int i = 0; i < 8; ++i) {                // w3l: 256 rows x 64 k
            int id = (i << 8) + tid, row = id >> 3, cc = id & 7;
            async16(w3 + (size_t)(n0 + row) * 512 + k0 + ((cc ^ (row & 7)) << 3),
                    &Bs[id << 3]);
        }
#pragma unroll
        for (int i = 0; i < 2; ++i) {                // fg: 64 rows x 64 k
            int id = (i << 8) + tid, row = id >> 3, cc = id & 7;
            async16(fgb + (size_t)row * 256 + k0 + ((cc ^ (row & 7)) << 3),
                    &As[id << 3]);
        }
        __syncthreads();
        const int q = lane >> 4, mr = lane & 15;
#pragma unroll
        for (int kk = 0; kk < 2; ++kk) {
            const int lc = (kk << 2) + q;
            short8 af[4], bfr[4];
#pragma unroll
            for (int mi = 0; mi < 4; ++mi) {
                int r = (mi << 4) + mr;
                af[mi] = *(const short8*)&As[r * 64 + ((lc ^ (r & 7)) << 3)];
            }
#pragma unroll
            for (int ni = 0; ni < 4; ++ni) {
                int r = (wave << 6) + (ni << 4) + mr;
                bfr[ni] = *(const short8*)&Bs[r * 64 + ((lc ^ (r & 7)) << 3)];
            }
#pragma unroll
            for (int mi = 0; mi < 4; ++mi)
#pragma unroll
                for (int ni = 0; ni < 4; ++ni)
                    acc[mi][ni] = __builtin_amdgcn_mfma_f32_16x16x32_bf16(af[mi], bfr[ni], acc[mi][ni], 0, 0, 0);
        }
    }
    const int q = lane >> 4, colb = lane & 15;
#pragma unroll
    for (int ni = 0; ni < 4; ++ni) {
        int n = n0 + (wave << 6) + (ni << 4) + colb;
        float s = bf2f(g2[n]) * rsqrtf(bf2f(v2[n]) + EPSV);
        float t = (bf2f(b3[n]) - bf2f(m2[n])) * s + bf2f(bb2[n]);
#pragma unroll
        for (int mi = 0; mi < 4; ++mi)
#pragma unroll
            for (int r = 0; r < 4; ++r) {
                int c = (mi << 4) + (q << 2) + r;
                th[((size_t)(b << 6) + c) * 512 + n] = fmaf(acc[mi][ni][r], s, t);
            }
    }
}

// ---- G34 v2: fused second_conv + out-proj + seg-max, register-budget-clean ----
// out = (relu(s*(feat.w3r^T) + th[choice])) . w4^T + b4 -> seg-max. h2 never
// touches global memory. 512 thr (8 waves, 2M x 4N), M=128/block.
// h2 computed in FOUR 128-col quarters: acc_a = 32 f/lane (not 64), so
// acc total = 32 + 96 = 128; arch ~100 -> ~228 <= 256 (validated bucket model;
// R1/R4 fusions died at 160 acc -> 270 > 256 -> spill).
// feat A (K=256) resident in LDS 64 KB: feat read ONCE (R1 design re-read 2x).
// LDS: Ar 64K + H 32K + U 48K = 144.5 KB -> 1 block/CU; regs cap occupancy at
// 2 waves/SIMD anyway (reg bucket), so nothing is lost vs 2-block configs.
__global__ __launch_bounds__(512, 2) void g34_out(
    const int* __restrict__ schoice, const u16* __restrict__ feat,
    const float* __restrict__ th, const u16* __restrict__ w3,
    const u16* __restrict__ w4, const u16* __restrict__ g2,
    const u16* __restrict__ v2, const u16* __restrict__ b4,
    unsigned int* __restrict__ out_u)
{
    __shared__ __align__(16) u16 Ar[128 * 256];   // 64 KB resident feat A
    __shared__ __align__(16) u16 H[128 * 128];    // 32 KB h2 quarter (swizzled)
    __shared__ __align__(16) u16 U[384 * 64];     // 48 KB union: w3q (16K) | w4 chunk
    __shared__ int chs[128];
    const int tid = threadIdx.x, lane = tid & 63, wave = tid >> 6;
    const int q = lane >> 4, mr = lane & 15, colb = lane & 15;
    const int wm  = (wave & 1) << 6;      // M offset (2 waves in M)
    const int wnA = (wave >> 1) << 5;     // phase-A N offset (4 x 32 in quarter)
    const int wnB = (wave >> 1) * 96;     // phase-B N offset (4 x 96 in 384)
    const int m0 = blockIdx.x << 7;
    if (tid < 128) chs[tid] = schoice[m0 + tid];
    // stage resident A: feat rows m0..+127, 256 cols, swizzled per 64-col group
#pragma unroll
    for (int i = 0; i < 8; ++i) {
        int id = (i << 9) + tid;                  // 0..4095 chunks
        int row = id >> 5, c32 = id & 31;
        int g64 = c32 >> 3, cc = c32 & 7;
        async16(feat + ((size_t)(m0 + row) << 8) + (g64 << 6) + ((cc ^ (row & 7)) << 3),
                &Ar[id << 3]);
    }
    const float* thb = th + ((size_t)((m0 >> 13) << 6) * 512);
    f32x4 acc_b[4][6] = {};
    for (int nq = 0; nq < 4; ++nq) {
        // ---- phase A: acc_a = feat . w3r[nq*128..+128]^T  (K=256) ----
        f32x4 acc_a[4][2] = {};
        for (int k0 = 0; k0 < 256; k0 += 64) {
            __syncthreads();                      // prior U readers done (also
                                                  // drains Ar staging on nq=0,k0=0)
#pragma unroll
            for (int i = 0; i < 2; ++i) {         // w3 quarter: 128 rows x 64 k
                int id = (i << 9) + tid, row = id >> 3, cc = id & 7;
                async16(w3 + (size_t)((nq << 7) + row) * 512 + 256 + k0
                            + ((cc ^ (row & 7)) << 3),
                        &U[id << 3]);
            }
            __syncthreads();                      // U ready
#pragma unroll
            for (int kk = 0; kk < 2; ++kk) {
                const int lc = (kk << 2) + q;
                short8 af[4], bfr[2];
#pragma unroll
                for (int mi = 0; mi < 4; ++mi) {
                    int r = wm + (mi << 4) + mr;
                    af[mi] = *(const short8*)&Ar[r * 256 + k0 + ((lc ^ (r & 7)) << 3)];
                }
#pragma unroll
                for (int ni = 0; ni < 2; ++ni) {
                    int r = wnA + (ni << 4) + mr;
                    bfr[ni] = *(const short8*)&U[r * 64 + ((lc ^ (r & 7)) << 3)];
                }
#pragma unroll
                for (int mi = 0; mi < 4; ++mi)
#pragma unroll
                    for (int ni = 0; ni < 2; ++ni)
                        acc_a[mi][ni] = __builtin_amdgcn_mfma_f32_16x16x32_bf16(af[mi], bfr[ni], acc_a[mi][ni], 0, 0, 0);
            }
        }
        // ---- bn2 + th + relu -> H quarter (A-operand swizzle) ----
        // safe vs other waves: all waves passed this quarter's phase-A barriers,
        // so their prior-quarter H reads are long done.
#pragma unroll
        for (int ni = 0; ni < 2; ++ni) {
            int ck = wnA + (ni << 4) + colb;      // 0..127 within quarter
            int n = (nq << 7) + ck;
            float s = bf2f(g2[n]) * rsqrtf(bf2f(v2[n]) + EPSV);
            int cchi = ck >> 3, clo = ck & 7;
#pragma unroll
            for (int mi = 0; mi < 4; ++mi)
#pragma unroll
                for (int r = 0; r < 4; ++r) {
                    int rr = wm + (mi << 4) + (q << 2) + r;
                    float thv = thb[(size_t)chs[rr] * 512 + n];
                    H[rr * 128 + ((cchi ^ (rr & 7)) << 3) + clo] =
                        f2bf(fmaxf(fmaf(acc_a[mi][ni][r], s, thv), 0.0f));
                }
        }
        // ---- phase B: acc_b += H(128x128) . w4[:, nq*128+kq]^T ----
        for (int kq = 0; kq < 128; kq += 64) {
            __syncthreads();                      // H writes visible; U reads done
#pragma unroll
            for (int i = 0; i < 6; ++i) {         // w4: 384 rows x 64 k
                int id = (i << 9) + tid, row = id >> 3, cc = id & 7;
                async16(w4 + (size_t)row * 512 + (nq << 7) + kq
                            + ((cc ^ (row & 7)) << 3),
                        &U[id << 3]);
            }
            __syncthreads();                      // U ready
#pragma unroll
            for (int kk = 0; kk < 2; ++kk) {
                const int lc = (kk << 2) + q;
                short8 af[4];
#pragma unroll
                for (int mi = 0; mi < 4; ++mi) {
                    int r = wm + (mi << 4) + mr;
                    af[mi] = *(const short8*)&H[r * 128 + (((kq >> 3) + (lc ^ (r & 7))) << 3)];
                }
#pragma unroll
                for (int ni = 0; ni < 6; ++ni) {
                    int r = wnB + (ni << 4) + mr;
                    short8 bfr = *(const short8*)&U[r * 64 + ((lc ^ (r & 7)) << 3)];
#pragma unroll
                    for (int mi = 0; mi < 4; ++mi)
                        acc_b[mi][ni] = __builtin_amdgcn_mfma_f32_16x16x32_bf16(af[mi], bfr, acc_b[mi][ni], 0, 0, 0);
                }
            }
        }
    }
    // ---- fused seg-max epilogue ----
    __syncthreads();                              // all LDS reads done; reuse Ar
    unsigned int* lred = (unsigned int*)Ar;       // 16384 u32 capacity
    const int kmin = chs[0], nk = chs[127] - kmin + 1;
    const bool useL = (nk <= 42);                 // nk*384 <= 16384
    const int bl = m0 >> 13;
    unsigned int* db = out_u + (size_t)(bl << 6) * 384;
    if (useL) for (int i = tid; i < nk * 384; i += 512) lred[i] = ENC_NINF;
    __syncthreads();
#pragma unroll
    for (int ni = 0; ni < 6; ++ni) {
        int nc = wnB + (ni << 4) + colb;
        float bv = bf2f(b4[nc]);
#pragma unroll
        for (int mi = 0; mi < 4; ++mi) {
            int curk = -1; unsigned int run = 0;
#pragma unroll
            for (int r = 0; r < 4; ++r) {
                int rr = wm + (mi << 4) + (q << 2) + r;
                unsigned int e = encbf(f2bf(acc_b[mi][ni][r] + bv));
                int k = chs[rr];
                if (k != curk) {
                    if (curk >= 0) {
                        if (useL) atomicMax(&lred[(curk - kmin) * 384 + nc], run);
                        else      atomicMax(&db[curk * 384 + nc], run);
                    }
                    curk = k; run = e;
                } else run = run > e ? run : e;
            }
            if (useL) atomicMax(&lred[(curk - kmin) * 384 + nc], run);
            else      atomicMax(&db[curk * 384 + nc], run);
        }
    }
    if (useL) {
        __syncthreads();
        for (int i = tid; i < nk * 384; i += 512) {
            unsigned int v = lred[i];
            if (v != ENC_NINF) {
                int kq = i / 384;
                atomicMax(&db[(kmin + kq) * 384 + (i - kq * 384)], v);
            }
        }
    }
}

__global__ __launch_bounds__(256) void k_dec_bf(const unsigned int* __restrict__ u,
                                                u16* __restrict__ o, int n)
{
    int i = blockIdx.x * 256 + threadIdx.x;
    if (i < n) o[i] = f2bf(dec(u[i]));
}
__global__ __launch_bounds__(256) void k_dec_f32(const unsigned int* __restrict__ u,
                                                 float* __restrict__ o, int n)
{
    int i = blockIdx.x * 256 + threadIdx.x;
    if (i < n) o[i] = dec(u[i]);
}

extern "C" void kernel_launch(void* const* d_in, const int* in_sizes, int n_in,
                              void* d_out, int out_size, void* d_ws, size_t ws_size,
                              hipStream_t stream)
{
    float* out = (float*)d_out;
    if (n_in != 18) {
        k_fillf<<<dim3((out_size + 255) / 256), 256, 0, stream>>>(out, out_size, 1000.0f);
        return;
    }

    const int map[17] = {0, 2, 3, 4, 5, 6, 7, 8, 9, 10, 11, 12, 13, 14, 15, 16, 17};
    Ptrs P;
    P.off[0] = 0;
    for (int i = 0; i < 17; ++i) {
        P.p[i] = d_in[map[i]];
        P.off[i + 1] = P.off[i] + in_sizes[map[i]];
    }
    P.chN = in_sizes[1];

    char* ws = (char*)d_ws;
    int* chi = (int*)ws;
    const size_t chiB = ((size_t)P.chN * 4 + 255) & ~255ull;
    int* schoice = (int*)(ws + chiB);
    int* perm    = (int*)(ws + 2 * chiB);
    u16* rp = (u16*)(ws + 3 * chiB);
    const size_t rpB = ((size_t)P.off[17] * 2 + 255) & ~255ull;
    const size_t RPB = 3 * chiB + rpB;

    // fixed region: fg_u (32*64*256 u32) + out_u (32*64*384 u32) = 5,242,880 B
    unsigned int* fg_u_all  = (unsigned int*)(ws + RPB);
    unsigned int* out_u_all = fg_u_all + 32 * 64 * 256;
    const size_t UB = 5242880ull;
    const int nU = 32 * 64 * 640;

    k_repack<<<dim3(1024), 256, 0, stream>>>(P, d_in[1], chi, rp, fg_u_all, nU);
    k_sort<<<dim3(P.chN >> 13), 256, 0, stream>>>(chi, schoice, perm);

    const u16* xyz  = rp + P.off[0];
    const u16* w1   = rp + P.off[1];
    const u16* b1   = rp + P.off[2];
    const u16* bn1g = rp + P.off[3];
    const u16* bn1b = rp + P.off[4];
    const u16* bn1m = rp + P.off[5];
    const u16* bn1v = rp + P.off[6];
    const u16* w2   = rp + P.off[7];
    const u16* b2   = rp + P.off[8];
    const u16* w3   = rp + P.off[9];
    const u16* b3   = rp + P.off[10];
    const u16* bn2g = rp + P.off[11];
    const u16* bn2b = rp + P.off[12];
    const u16* bn2m = rp + P.off[13];
    const u16* bn2v = rp + P.off[14];
    const u16* w4   = rp + P.off[15];
    const u16* b4   = rp + P.off[16];

    // per-batch: feat 4,194,304 + fg 32,768 + th 131,072 = 4,358,144 (h2 gone)
    const size_t PB = 4358144ull;
    int sb = 32;
    while (sb > 1 && RPB + UB + (size_t)sb * PB > ws_size) sb >>= 1;
    if (RPB + UB + PB > ws_size) {
        k_fillf<<<dim3((out_size + 255) / 256), 256, 0, stream>>>(out, out_size, 3000.0f);
        return;
    }
    const int ns = 32 / sb;

    char* wsb = ws + RPB + UB;
    const size_t featB = (size_t)sb * 8192 * 256 * 2;
    const size_t fgB   = (size_t)sb * 64 * 256 * 2;
    u16* feat = (u16*)(wsb);
    u16* fg   = (u16*)(wsb + featB);
    float* th = (float*)(wsb + featB + fgB);

    const int mblk = sb << 6;        // 128-row M-tiles
    const int nfg = sb * 64 * 256;
    const int nou = sb * 64 * 384;
    for (int s = 0; s < ns; ++s) {
        const int b0 = s * sb;
        const int pt0 = b0 << 13;
        const int* sch_sl = schoice + pt0;
        const int* perm_sl = perm + pt0;
        unsigned int* fg_u  = fg_u_all + (size_t)b0 * 64 * 256;
        unsigned int* out_u = out_u_all + (size_t)b0 * 64 * 384;
        g1_feat<<<dim3(mblk), 256, 0, stream>>>(xyz, w1, b1, bn1g, bn1b, bn1m, bn1v,
                                                w2, b2, sch_sl, perm_sl, feat, fg_u);
        k_dec_bf<<<dim3((nfg + 255) / 256), 256, 0, stream>>>(fg_u, fg, nfg);
        k_th<<<dim3(sb, 2), 256, 0, stream>>>(fg, w3, b3, bn2g, bn2b, bn2m, bn2v, th);
        g34_out<<<dim3(mblk), 512, 0, stream>>>(sch_sl, feat, th, w3, w4,
                                                bn2g, bn2v, b4, out_u);
        k_dec_f32<<<dim3((nou + 255) / 256), 256, 0, stream>>>(out_u,
                                                               out + ((size_t)b0 << 6) * 384, nou);
    }
}